// Round 4
// baseline (706.464 us; speedup 1.0000x reference)
//
#include <hip/hip_runtime.h>

#define BB 16
#define NN 2048
#define DD 128

typedef __attribute__((ext_vector_type(8))) __bf16 bf16x8;
typedef __attribute__((ext_vector_type(4))) float f32x4;
typedef __attribute__((ext_vector_type(4))) unsigned int u32x4;
typedef __attribute__((address_space(3))) unsigned int lds_u32;
typedef __attribute__((address_space(1))) const unsigned int glob_u32;

static __device__ __forceinline__ unsigned short f2b(float f) {
  union { float f; unsigned int u; } c; c.f = f;
  unsigned int u = c.u;
  unsigned int r = (u + 0x7FFFu + ((u >> 16) & 1u)) >> 16;
  return (unsigned short)r;
}
static __device__ __forceinline__ float b2f(unsigned short u) {
  union { unsigned int u; float f; } c; c.u = ((unsigned int)u) << 16;
  return c.f;
}

// WT[l][e][d] = bf16(W[l][d][e])  -- 96 KB total, L2-resident afterwards
__global__ void k_wt(const float* __restrict__ W, unsigned short* __restrict__ WT) {
  __shared__ float t[64][65];
  int l = blockIdx.z, d0 = blockIdx.x * 64, e0 = blockIdx.y * 64;
  int tid = threadIdx.x;
  const float* src = W + (size_t)l * DD * DD;
  for (int p = 0; p < 16; ++p) {
    int idx = p * 256 + tid;
    int d = idx >> 6, e = idx & 63;
    t[e][d] = src[(size_t)(d0 + d) * DD + (e0 + e)];
  }
  __syncthreads();
  unsigned short* dst = WT + (size_t)l * DD * DD;
  for (int p = 0; p < 4; ++p) {
    int idx = p * 256 + tid;
    int e = idx >> 4, d4 = (idx & 15) * 4;
    ushort4 r;
    r.x = f2b(t[e][d4 + 0]); r.y = f2b(t[e][d4 + 1]);
    r.z = f2b(t[e][d4 + 2]); r.w = f2b(t[e][d4 + 3]);
    *(ushort4*)(dst + (size_t)(e0 + e) * DD + (d0 + d4)) = r;
  }
}

// Merged: x<1024 -> adj transpose tile (float4 reads); x>=1024 -> layer-0 gemm1
__global__ __launch_bounds__(256) void k_pre(const float* __restrict__ adj,
                                             unsigned short* __restrict__ adjT,
                                             const float* __restrict__ X,
                                             const unsigned short* __restrict__ WT,
                                             unsigned short* __restrict__ hwT) {
  int b = blockIdx.y, x = blockIdx.x, tid = threadIdx.x;
  if (x < 1024) {
    __shared__ float t[64][65];
    int j0 = (x >> 5) * 64, i0 = (x & 31) * 64;
    const float* src = adj + (size_t)b * NN * NN;
#pragma unroll
    for (int p = 0; p < 4; ++p) {
      int idx = p * 256 + tid;
      int i = idx >> 4, c4 = (idx & 15) * 4;
      float4 v = *(const float4*)(src + (size_t)(i0 + i) * NN + (j0 + c4));
      t[c4 + 0][i] = v.x; t[c4 + 1][i] = v.y;
      t[c4 + 2][i] = v.z; t[c4 + 3][i] = v.w;
    }
    __syncthreads();
    unsigned short* dst = adjT + (size_t)b * NN * NN;
#pragma unroll
    for (int p = 0; p < 4; ++p) {
      int idx = p * 256 + tid;
      int j = idx >> 4, i4 = (idx & 15) * 4;
      ushort4 r;
      r.x = f2b(t[j][i4 + 0]); r.y = f2b(t[j][i4 + 1]);
      r.z = f2b(t[j][i4 + 2]); r.w = f2b(t[j][i4 + 3]);
      *(ushort4*)(dst + (size_t)(j0 + j) * NN + (i0 + i4)) = r;
    }
  } else {
    int i0 = (x - 1024) * 64;
    int lane = tid & 63, w = tid >> 6;
    int q = lane >> 4, m = lane & 15;
    f32x4 acc[8];
#pragma unroll
    for (int t = 0; t < 8; ++t)
#pragma unroll
      for (int r = 0; r < 4; ++r) acc[t][r] = 0.f;
    int irow = i0 + w * 16 + m;
    const float* hrow = X + ((size_t)b * NN + irow) * DD;
#pragma unroll
    for (int kk = 0; kk < 4; ++kk) {
      int d0 = kk * 32 + q * 8;
      float4 h0 = *(const float4*)(hrow + d0);
      float4 h1 = *(const float4*)(hrow + d0 + 4);
      union { bf16x8 v; unsigned short s[8]; } ub;
      ub.s[0] = f2b(h0.x); ub.s[1] = f2b(h0.y); ub.s[2] = f2b(h0.z); ub.s[3] = f2b(h0.w);
      ub.s[4] = f2b(h1.x); ub.s[5] = f2b(h1.y); ub.s[6] = f2b(h1.z); ub.s[7] = f2b(h1.w);
#pragma unroll
      for (int mt = 0; mt < 8; ++mt) {
        bf16x8 af = *(const bf16x8*)(WT + (mt * 16 + m) * 128 + d0);
        acc[mt] = __builtin_amdgcn_mfma_f32_16x16x32_bf16(af, ub.v, acc[mt], 0, 0, 0);
      }
    }
    unsigned short* dst = hwT + (size_t)b * DD * NN;
#pragma unroll
    for (int mt = 0; mt < 8; ++mt)
#pragma unroll
      for (int r = 0; r < 4; ++r)
        dst[(size_t)(mt * 16 + q * 4 + r) * NN + irow] = f2b(acc[mt][r]);
  }
}

// Fused per-layer kernel, 2-phase pipelined (R2 structure, best measured config).
__global__ __launch_bounds__(256) void k_layer(const unsigned short* __restrict__ adjT,
                                               const unsigned short* __restrict__ hwT,
                                               const float* __restrict__ res,
                                               const float* __restrict__ bias,
                                               const float* __restrict__ gamma,
                                               const float* __restrict__ beta,
                                               const unsigned short* __restrict__ WTn,
                                               float* __restrict__ outf,
                                               unsigned short* __restrict__ hwTn,
                                               int doW) {
  __shared__ __align__(16) unsigned short sbuf[2 * 12288];  // 2 x (sA 4096 + sH 8192)
  __shared__ float smu[64], srs[64];
  float* z = (float*)sbuf;  // 64x132 f32 = 33.8 KB, alias: staging dead after K-loop

  int tid = threadIdx.x;
  int lane = tid & 63, w = tid >> 6;
  int q = lane >> 4, m = lane & 15;
  int wj = w & 1, we = w >> 1;
  int b = blockIdx.y, j0 = blockIdx.x * 64;
  const unsigned short* At = adjT + (size_t)b * NN * NN;
  const unsigned short* Ht = hwT + (size_t)b * DD * NN;

  // Pre-swizzled global source, linear LDS dest (both-sides-or-neither rule).
  const unsigned short* aSrc[2];
  const unsigned short* hSrc[4];
#pragma unroll
  for (int it = 0; it < 2; ++it) {
    int p = (it * 4 + w) * 64 + lane;
    int r = p >> 3, cg = (p & 7) ^ (r & 7);
    aSrc[it] = At + (size_t)(j0 + r) * NN + cg * 8;
  }
#pragma unroll
  for (int it = 0; it < 4; ++it) {
    int p = (it * 4 + w) * 64 + lane;
    int r = p >> 3, cg = (p & 7) ^ (r & 7);
    hSrc[it] = Ht + (size_t)r * NN + cg * 8;
  }

  f32x4 acc[2][4];
#pragma unroll
  for (int i = 0; i < 2; ++i)
#pragma unroll
    for (int j = 0; j < 4; ++j)
#pragma unroll
      for (int r = 0; r < 4; ++r) acc[i][j][r] = 0.f;

  // Prologue: stage tile 0 into buf0
#pragma unroll
  for (int it = 0; it < 2; ++it) {
    __builtin_amdgcn_global_load_lds((glob_u32*)aSrc[it],
                                     (lds_u32*)(sbuf + (it * 4 + w) * 512), 16, 0, 0);
    aSrc[it] += 64;
  }
#pragma unroll
  for (int it = 0; it < 4; ++it) {
    __builtin_amdgcn_global_load_lds((glob_u32*)hSrc[it],
                                     (lds_u32*)(sbuf + 4096 + (it * 4 + w) * 512), 16, 0, 0);
    hSrc[it] += 64;
  }
  __syncthreads();

  for (int t = 0; t < 32; ++t) {
    const unsigned short* sA = sbuf + (t & 1) * 12288;
    const unsigned short* sH = sA + 4096;
    if (t < 31) {  // issue next-tile loads first: they fly under ds_read+MFMA
      unsigned short* nA = sbuf + ((t + 1) & 1) * 12288;
      unsigned short* nH = nA + 4096;
#pragma unroll
      for (int it = 0; it < 2; ++it) {
        __builtin_amdgcn_global_load_lds((glob_u32*)aSrc[it],
                                         (lds_u32*)(nA + (it * 4 + w) * 512), 16, 0, 0);
        aSrc[it] += 64;
      }
#pragma unroll
      for (int it = 0; it < 4; ++it) {
        __builtin_amdgcn_global_load_lds((glob_u32*)hSrc[it],
                                         (lds_u32*)(nH + (it * 4 + w) * 512), 16, 0, 0);
        hSrc[it] += 64;
      }
    }
#pragma unroll
    for (int kk = 0; kk < 2; ++kk) {
      bf16x8 af[2], bfr[4];
#pragma unroll
      for (int mt = 0; mt < 2; ++mt) {
        int r = wj * 32 + mt * 16 + m;
        int c = (kk * 4 + q) ^ (r & 7);
        af[mt] = *(const bf16x8*)(sA + r * 64 + c * 8);
      }
#pragma unroll
      for (int nt = 0; nt < 4; ++nt) {
        int r = we * 64 + nt * 16 + m;
        int c = (kk * 4 + q) ^ (r & 7);
        bfr[nt] = *(const bf16x8*)(sH + r * 64 + c * 8);
      }
#pragma unroll
      for (int mt = 0; mt < 2; ++mt)
#pragma unroll
        for (int nt = 0; nt < 4; ++nt)
          acc[mt][nt] = __builtin_amdgcn_mfma_f32_16x16x32_bf16(af[mt], bfr[nt], acc[mt][nt], 0, 0, 0);
    }
    __syncthreads();  // vmcnt(0): next tile resident; lgkm done; buf reuse safe
  }

  // E1: spill accumulators (full-K fp32 sums) into z
#pragma unroll
  for (int mt = 0; mt < 2; ++mt)
#pragma unroll
    for (int nt = 0; nt < 4; ++nt)
#pragma unroll
      for (int r = 0; r < 4; ++r) {
        int row = wj * 32 + mt * 16 + q * 4 + r;
        int col = we * 64 + nt * 16 + m;
        z[row * 132 + col] = acc[mt][nt][r];
      }
  __syncthreads();

  // E2: z += res + bias
  size_t base = ((size_t)b * NN + j0) * DD;
#pragma unroll
  for (int p = 0; p < 4; ++p) {
    int idx = p * 256 + tid;
    int j = idx >> 4, c8 = (idx & 15) * 8;
    size_t off = (size_t)j * DD + c8;
    const float4* r4 = (const float4*)(res + base + off);
    float4 r0 = r4[0], r1 = r4[1];
    const float4* bi4 = (const float4*)(bias + c8);
    float4 b0 = bi4[0], b1 = bi4[1];
    float* zz = &z[j * 132 + c8];
    zz[0] += r0.x + b0.x; zz[1] += r0.y + b0.y;
    zz[2] += r0.z + b0.z; zz[3] += r0.w + b0.w;
    zz[4] += r1.x + b1.x; zz[5] += r1.y + b1.y;
    zz[6] += r1.z + b1.z; zz[7] += r1.w + b1.w;
  }
  __syncthreads();

  // E3: LN stats (4 threads per row, interleaved reads; 2-way bank = free)
  {
    int j = tid >> 2, s = tid & 3;
    float sum = 0.f, sq = 0.f;
#pragma unroll
    for (int k = 0; k < 32; ++k) {
      float v = z[j * 132 + s + 4 * k];
      sum += v; sq += v * v;
    }
    sum += __shfl_xor(sum, 1); sq += __shfl_xor(sq, 1);
    sum += __shfl_xor(sum, 2); sq += __shfl_xor(sq, 2);
    if (s == 0) {
      float mu = sum * (1.f / 128.f);
      float var = sq * (1.f / 128.f) - mu * mu;
      smu[j] = mu;
      srs[j] = rsqrtf(var + 1e-5f);
    }
  }
  __syncthreads();

  // E4: normalize + ReLU -> outf; keep h in z for gemm1
  {
    int e = tid & 127;
    float g = gamma[e], bt = beta[e];
#pragma unroll
    for (int p = 0; p < 32; ++p) {
      int idx = p * 256 + tid;
      int j = idx >> 7;
      float v = (z[j * 132 + e] - smu[j]) * srs[j] * g + bt;
      v = fmaxf(v, 0.f);
      outf[base + idx] = v;
      z[j * 132 + e] = v;   // same thread, same slot: no race
    }
  }
  if (!doW) return;
  __syncthreads();

  // E5: gemm1 -> hwTn[e][irow]; WTn fragments direct from global (L2-hot, 32 KB)
  f32x4 acc2[8];
#pragma unroll
  for (int t = 0; t < 8; ++t)
#pragma unroll
    for (int r = 0; r < 4; ++r) acc2[t][r] = 0.f;
  int irow = j0 + w * 16 + m;
  const float* hrow = &z[(w * 16 + m) * 132];
#pragma unroll
  for (int kk = 0; kk < 4; ++kk) {
    int d0 = kk * 32 + q * 8;
    float4 h0 = *(const float4*)(hrow + d0);
    float4 h1 = *(const float4*)(hrow + d0 + 4);
    union { bf16x8 v; unsigned short s[8]; } ub;
    ub.s[0] = f2b(h0.x); ub.s[1] = f2b(h0.y); ub.s[2] = f2b(h0.z); ub.s[3] = f2b(h0.w);
    ub.s[4] = f2b(h1.x); ub.s[5] = f2b(h1.y); ub.s[6] = f2b(h1.z); ub.s[7] = f2b(h1.w);
#pragma unroll
    for (int mt = 0; mt < 8; ++mt) {
      bf16x8 af = *(const bf16x8*)(WTn + (mt * 16 + m) * 128 + d0);
      acc2[mt] = __builtin_amdgcn_mfma_f32_16x16x32_bf16(af, ub.v, acc2[mt], 0, 0, 0);
    }
  }
  unsigned short* dst = hwTn + (size_t)b * DD * NN;
#pragma unroll
  for (int mt = 0; mt < 8; ++mt)
#pragma unroll
    for (int r = 0; r < 4; ++r)
      dst[(size_t)(mt * 16 + q * 4 + r) * NN + irow] = f2b(acc2[mt][r]);
}

extern "C" void kernel_launch(void* const* d_in, const int* in_sizes, int n_in,
                              void* d_out, int out_size, void* d_ws, size_t ws_size,
                              hipStream_t stream) {
  const float* X   = (const float*)d_in[0];
  const float* adj = (const float*)d_in[1];
  const float* Ws  = (const float*)d_in[2];
  const float* bs  = (const float*)d_in[3];
  const float* gms = (const float*)d_in[4];
  const float* bts = (const float*)d_in[5];
  float* out = (float*)d_out;

  // ws: adjT bf16 (134MB) | hwT ping-pong bf16 (2 x 8.4MB) | WT bf16 (96KB)
  unsigned short* adjT = (unsigned short*)d_ws;
  unsigned short* hwT0 = adjT + (size_t)BB * NN * NN;
  unsigned short* hwT1 = hwT0 + (size_t)BB * DD * NN;
  unsigned short* WT   = hwT1 + (size_t)BB * DD * NN;

  k_wt<<<dim3(2, 2, 3), 256, 0, stream>>>(Ws, WT);
  // ===== TIMING PROBE (this round only): k_pre is idempotent; launch 3x.
  // dur_us = base + 2*T(k_pre). Resolves the k_pre vs k_layer split that three
  // neutral rounds of blind k_layer optimization could not.
  k_pre<<<dim3(1056, BB), 256, 0, stream>>>(adj, adjT, X, WT, hwT0);
  k_pre<<<dim3(1056, BB), 256, 0, stream>>>(adj, adjT, X, WT, hwT0);
  k_pre<<<dim3(1056, BB), 256, 0, stream>>>(adj, adjT, X, WT, hwT0);
  for (int l = 0; l < 3; ++l) {
    const float* res = (l == 0) ? X : (const float*)out;
    const unsigned short* WTn = WT + (size_t)((l < 2) ? (l + 1) : 0) * DD * DD;
    unsigned short* hin  = (l & 1) ? hwT1 : hwT0;
    unsigned short* hout = (l & 1) ? hwT0 : hwT1;
    k_layer<<<dim3(NN / 64, BB), 256, 0, stream>>>(adjT, hin, res, bs + l * DD,
                                                   gms + l * DD, bts + l * DD,
                                                   WTn, out, hout, (l < 2) ? 1 : 0);
  }
}

// Round 5
// 534.144 us; speedup vs baseline: 1.3226x; 1.3226x over previous
//
#include <hip/hip_runtime.h>

#define BB 16
#define NN 2048
#define DD 128

typedef __attribute__((ext_vector_type(8))) __bf16 bf16x8;
typedef __attribute__((ext_vector_type(4))) float f32x4;
typedef __attribute__((ext_vector_type(4))) unsigned int u32x4;
typedef __attribute__((address_space(3))) unsigned int lds_u32;
typedef __attribute__((address_space(1))) const unsigned int glob_u32;

static __device__ __forceinline__ unsigned short f2b(float f) {
  union { float f; unsigned int u; } c; c.f = f;
  unsigned int u = c.u;
  unsigned int r = (u + 0x7FFFu + ((u >> 16) & 1u)) >> 16;
  return (unsigned short)r;
}
static __device__ __forceinline__ float b2f(unsigned short u) {
  union { unsigned int u; float f; } c; c.u = ((unsigned int)u) << 16;
  return c.f;
}

// ===== Tiled layouts (all K-loop staging streams are contiguous) =====
// adjTt[b][jt][kt][p=0..511]  8KB tiles; chunk p (16B) holds
//   adjT[jt*64 + (p>>3)][kt*64 + ((p&7)^((p>>3)&7))*8 + s]   (XOR swizzle baked in)
// hwTt[b][kt][p=0..1023] 16KB tiles; chunk p holds
//   hwT[e=(p>>3)][kt*64 + ((p&7)^((p>>3)&7))*8 + s]
// These match k_layer's LDS image exactly -> staging = linear copy.

// WT[l][e][d] = bf16(W[l][d][e])  -- 96 KB total, L2-resident afterwards
__global__ void k_wt(const float* __restrict__ W, unsigned short* __restrict__ WT) {
  __shared__ float t[64][65];
  int l = blockIdx.z, d0 = blockIdx.x * 64, e0 = blockIdx.y * 64;
  int tid = threadIdx.x;
  const float* src = W + (size_t)l * DD * DD;
  for (int p = 0; p < 16; ++p) {
    int idx = p * 256 + tid;
    int d = idx >> 6, e = idx & 63;
    t[e][d] = src[(size_t)(d0 + d) * DD + (e0 + e)];
  }
  __syncthreads();
  unsigned short* dst = WT + (size_t)l * DD * DD;
  for (int p = 0; p < 4; ++p) {
    int idx = p * 256 + tid;
    int e = idx >> 4, d4 = (idx & 15) * 4;
    ushort4 r;
    r.x = f2b(t[e][d4 + 0]); r.y = f2b(t[e][d4 + 1]);
    r.z = f2b(t[e][d4 + 2]); r.w = f2b(t[e][d4 + 3]);
    *(ushort4*)(dst + (size_t)(e0 + e) * DD + (d0 + d4)) = r;
  }
}

// x<256: transpose adj -> tiled adjTt. Block = 64 i-rows x 256 j-cols:
//   reads 1KB contiguous per adj row; writes 4 tiles as contiguous 16B chunks.
// x>=256: layer-0 gemm1 -> tiled hwTt (one 16KB tile per block).
__global__ __launch_bounds__(256) void k_pre(const float* __restrict__ adj,
                                             unsigned short* __restrict__ adjTt,
                                             const float* __restrict__ X,
                                             const unsigned short* __restrict__ WT,
                                             unsigned short* __restrict__ hwTt) {
  __shared__ unsigned short t2[64 * 260];  // t2[i][j] bf16, 33.3 KB
  int b = blockIdx.y, x = blockIdx.x, tid = threadIdx.x;
  if (x < 256) {
    int i_t = x >> 3, j_t = x & 7;
    int i0 = i_t * 64, j0 = j_t * 256;
    const float* src = adj + (size_t)b * NN * NN;
#pragma unroll
    for (int p = 0; p < 16; ++p) {
      int idx = p * 256 + tid;
      int i = idx >> 6, jc = (idx & 63) * 4;
      float4 v = *(const float4*)(src + (size_t)(i0 + i) * NN + (j0 + jc));
      unsigned int* d = (unsigned int*)(t2 + i * 260 + jc);
      d[0] = (unsigned int)f2b(v.x) | ((unsigned int)f2b(v.y) << 16);
      d[1] = (unsigned int)f2b(v.z) | ((unsigned int)f2b(v.w) << 16);
    }
    __syncthreads();
    // 4 subtiles (jt = j_t*4+sub, kt = i_t), 512 chunks each, contiguous writes
#pragma unroll
    for (int pp = 0; pp < 8; ++pp) {
      int idx = pp * 256 + tid;
      int sub = idx >> 9, p = idx & 511;
      int r = p >> 3, g = (p & 7) ^ (r & 7);
      union { u32x4 u; unsigned short h[8]; } ub;
#pragma unroll
      for (int s = 0; s < 8; ++s) ub.h[s] = t2[(g * 8 + s) * 260 + sub * 64 + r];
      size_t tile = ((size_t)(b * 32 + j_t * 4 + sub) * 32 + i_t) * 4096;
      *(u32x4*)(adjTt + tile + p * 8) = ub.u;
    }
  } else {
    int kt = x - 256;
    int i0 = kt * 64;
    int lane = tid & 63, w = tid >> 6;
    int q = lane >> 4, m = lane & 15;
    f32x4 acc[8];
#pragma unroll
    for (int t = 0; t < 8; ++t)
#pragma unroll
      for (int r = 0; r < 4; ++r) acc[t][r] = 0.f;
    int il = w * 16 + m;
    const float* hrow = X + ((size_t)b * NN + i0 + il) * DD;
#pragma unroll
    for (int kk = 0; kk < 4; ++kk) {
      int d0 = kk * 32 + q * 8;
      float4 h0 = *(const float4*)(hrow + d0);
      float4 h1 = *(const float4*)(hrow + d0 + 4);
      union { bf16x8 v; unsigned short s[8]; } ub;
      ub.s[0] = f2b(h0.x); ub.s[1] = f2b(h0.y); ub.s[2] = f2b(h0.z); ub.s[3] = f2b(h0.w);
      ub.s[4] = f2b(h1.x); ub.s[5] = f2b(h1.y); ub.s[6] = f2b(h1.z); ub.s[7] = f2b(h1.w);
#pragma unroll
      for (int mt = 0; mt < 8; ++mt) {
        bf16x8 af = *(const bf16x8*)(WT + (mt * 16 + m) * 128 + d0);
        acc[mt] = __builtin_amdgcn_mfma_f32_16x16x32_bf16(af, ub.v, acc[mt], 0, 0, 0);
      }
    }
    // write one full 16KB hwTt tile (kt); 16-lane groups write 32B-contiguous runs
    unsigned short* dst = hwTt + ((size_t)b * 32 + kt) * 8192;
#pragma unroll
    for (int mt = 0; mt < 8; ++mt)
#pragma unroll
      for (int r = 0; r < 4; ++r) {
        int e = mt * 16 + q * 4 + r;
        int p = e * 8 + ((il >> 3) ^ (e & 7));
        dst[p * 8 + (il & 7)] = f2b(acc[mt][r]);
      }
  }
}

// Fused per-layer kernel, 2-phase pipelined; staging now reads CONTIGUOUS tiles
// (8KB adjTt + 16KB hwTt per iter) -> pure DRAM/L2 streaming. LDS image and
// MFMA code identical to the verified R2 version.
__global__ __launch_bounds__(256) void k_layer(const unsigned short* __restrict__ adjTt,
                                               const unsigned short* __restrict__ hwTt,
                                               const float* __restrict__ res,
                                               const float* __restrict__ bias,
                                               const float* __restrict__ gamma,
                                               const float* __restrict__ beta,
                                               const unsigned short* __restrict__ WTn,
                                               float* __restrict__ outf,
                                               unsigned short* __restrict__ hwTnt,
                                               int doW) {
  __shared__ __align__(16) unsigned short sbuf[2 * 12288];  // 2 x (sA 4096 + sH 8192)
  __shared__ float smu[64], srs[64];
  float* z = (float*)sbuf;  // 64x132 f32 = 33.8 KB, alias: staging dead after K-loop

  int tid = threadIdx.x;
  int lane = tid & 63, w = tid >> 6;
  int q = lane >> 4, m = lane & 15;
  int wj = w & 1, we = w >> 1;
  int b = blockIdx.y, jt = blockIdx.x, j0 = jt * 64;
  const unsigned short* At = adjTt + ((size_t)(b * 32 + jt)) * 32 * 4096;
  const unsigned short* Ht = hwTt + (size_t)b * 32 * 8192;

  // Linear tile staging: chunk index == LDS chunk index.
  const unsigned short* aSrc[2];
  const unsigned short* hSrc[4];
#pragma unroll
  for (int it = 0; it < 2; ++it)
    aSrc[it] = At + ((it * 4 + w) * 64 + lane) * 8;
#pragma unroll
  for (int it = 0; it < 4; ++it)
    hSrc[it] = Ht + ((it * 4 + w) * 64 + lane) * 8;

  f32x4 acc[2][4];
#pragma unroll
  for (int i = 0; i < 2; ++i)
#pragma unroll
    for (int j = 0; j < 4; ++j)
#pragma unroll
      for (int r = 0; r < 4; ++r) acc[i][j][r] = 0.f;

  // Prologue: stage tile 0 into buf0
#pragma unroll
  for (int it = 0; it < 2; ++it) {
    __builtin_amdgcn_global_load_lds((glob_u32*)aSrc[it],
                                     (lds_u32*)(sbuf + (it * 4 + w) * 512), 16, 0, 0);
    aSrc[it] += 4096;
  }
#pragma unroll
  for (int it = 0; it < 4; ++it) {
    __builtin_amdgcn_global_load_lds((glob_u32*)hSrc[it],
                                     (lds_u32*)(sbuf + 4096 + (it * 4 + w) * 512), 16, 0, 0);
    hSrc[it] += 8192;
  }
  __syncthreads();

  for (int t = 0; t < 32; ++t) {
    const unsigned short* sA = sbuf + (t & 1) * 12288;
    const unsigned short* sH = sA + 4096;
    if (t < 31) {  // issue next-tile loads first: they fly under ds_read+MFMA
      unsigned short* nA = sbuf + ((t + 1) & 1) * 12288;
      unsigned short* nH = nA + 4096;
#pragma unroll
      for (int it = 0; it < 2; ++it) {
        __builtin_amdgcn_global_load_lds((glob_u32*)aSrc[it],
                                         (lds_u32*)(nA + (it * 4 + w) * 512), 16, 0, 0);
        aSrc[it] += 4096;
      }
#pragma unroll
      for (int it = 0; it < 4; ++it) {
        __builtin_amdgcn_global_load_lds((glob_u32*)hSrc[it],
                                         (lds_u32*)(nH + (it * 4 + w) * 512), 16, 0, 0);
        hSrc[it] += 8192;
      }
    }
#pragma unroll
    for (int kk = 0; kk < 2; ++kk) {
      bf16x8 af[2], bfr[4];
#pragma unroll
      for (int mt = 0; mt < 2; ++mt) {
        int r = wj * 32 + mt * 16 + m;
        int c = (kk * 4 + q) ^ (r & 7);
        af[mt] = *(const bf16x8*)(sA + r * 64 + c * 8);
      }
#pragma unroll
      for (int nt = 0; nt < 4; ++nt) {
        int r = we * 64 + nt * 16 + m;
        int c = (kk * 4 + q) ^ (r & 7);
        bfr[nt] = *(const bf16x8*)(sH + r * 64 + c * 8);
      }
#pragma unroll
      for (int mt = 0; mt < 2; ++mt)
#pragma unroll
        for (int nt = 0; nt < 4; ++nt)
          acc[mt][nt] = __builtin_amdgcn_mfma_f32_16x16x32_bf16(af[mt], bfr[nt], acc[mt][nt], 0, 0, 0);
    }
    __syncthreads();  // vmcnt(0): next tile resident; lgkm done; buf reuse safe
  }

  // E1: spill accumulators (full-K fp32 sums) into z
#pragma unroll
  for (int mt = 0; mt < 2; ++mt)
#pragma unroll
    for (int nt = 0; nt < 4; ++nt)
#pragma unroll
      for (int r = 0; r < 4; ++r) {
        int row = wj * 32 + mt * 16 + q * 4 + r;
        int col = we * 64 + nt * 16 + m;
        z[row * 132 + col] = acc[mt][nt][r];
      }
  __syncthreads();

  // E2: z += res + bias
  size_t base = ((size_t)b * NN + j0) * DD;
#pragma unroll
  for (int p = 0; p < 4; ++p) {
    int idx = p * 256 + tid;
    int j = idx >> 4, c8 = (idx & 15) * 8;
    size_t off = (size_t)j * DD + c8;
    const float4* r4 = (const float4*)(res + base + off);
    float4 r0 = r4[0], r1 = r4[1];
    const float4* bi4 = (const float4*)(bias + c8);
    float4 b0 = bi4[0], b1 = bi4[1];
    float* zz = &z[j * 132 + c8];
    zz[0] += r0.x + b0.x; zz[1] += r0.y + b0.y;
    zz[2] += r0.z + b0.z; zz[3] += r0.w + b0.w;
    zz[4] += r1.x + b1.x; zz[5] += r1.y + b1.y;
    zz[6] += r1.z + b1.z; zz[7] += r1.w + b1.w;
  }
  __syncthreads();

  // E3: LN stats (4 threads per row, interleaved reads; 2-way bank = free)
  {
    int j = tid >> 2, s = tid & 3;
    float sum = 0.f, sq = 0.f;
#pragma unroll
    for (int k = 0; k < 32; ++k) {
      float v = z[j * 132 + s + 4 * k];
      sum += v; sq += v * v;
    }
    sum += __shfl_xor(sum, 1); sq += __shfl_xor(sq, 1);
    sum += __shfl_xor(sum, 2); sq += __shfl_xor(sq, 2);
    if (s == 0) {
      float mu = sum * (1.f / 128.f);
      float var = sq * (1.f / 128.f) - mu * mu;
      smu[j] = mu;
      srs[j] = rsqrtf(var + 1e-5f);
    }
  }
  __syncthreads();

  // E4: normalize + ReLU -> outf; keep h in z for gemm1
  {
    int e = tid & 127;
    float g = gamma[e], bt = beta[e];
#pragma unroll
    for (int p = 0; p < 32; ++p) {
      int idx = p * 256 + tid;
      int j = idx >> 7;
      float v = (z[j * 132 + e] - smu[j]) * srs[j] * g + bt;
      v = fmaxf(v, 0.f);
      outf[base + idx] = v;
      z[j * 132 + e] = v;   // same thread, same slot: no race
    }
  }
  if (!doW) return;
  __syncthreads();

  // E5: gemm1 -> tiled hwTnt tile (kt = jt); WTn fragments direct from global
  f32x4 acc2[8];
#pragma unroll
  for (int t = 0; t < 8; ++t)
#pragma unroll
    for (int r = 0; r < 4; ++r) acc2[t][r] = 0.f;
  int il = w * 16 + m;
  const float* hrow = &z[il * 132];
#pragma unroll
  for (int kk = 0; kk < 4; ++kk) {
    int d0 = kk * 32 + q * 8;
    float4 h0 = *(const float4*)(hrow + d0);
    float4 h1 = *(const float4*)(hrow + d0 + 4);
    union { bf16x8 v; unsigned short s[8]; } ub;
    ub.s[0] = f2b(h0.x); ub.s[1] = f2b(h0.y); ub.s[2] = f2b(h0.z); ub.s[3] = f2b(h0.w);
    ub.s[4] = f2b(h1.x); ub.s[5] = f2b(h1.y); ub.s[6] = f2b(h1.z); ub.s[7] = f2b(h1.w);
#pragma unroll
    for (int mt = 0; mt < 8; ++mt) {
      bf16x8 af = *(const bf16x8*)(WTn + (mt * 16 + m) * 128 + d0);
      acc2[mt] = __builtin_amdgcn_mfma_f32_16x16x32_bf16(af, ub.v, acc2[mt], 0, 0, 0);
    }
  }
  unsigned short* dst = hwTnt + ((size_t)b * 32 + jt) * 8192;
#pragma unroll
  for (int mt = 0; mt < 8; ++mt)
#pragma unroll
    for (int r = 0; r < 4; ++r) {
      int e = mt * 16 + q * 4 + r;
      int p = e * 8 + ((il >> 3) ^ (e & 7));
      dst[p * 8 + (il & 7)] = f2b(acc2[mt][r]);
    }
}

extern "C" void kernel_launch(void* const* d_in, const int* in_sizes, int n_in,
                              void* d_out, int out_size, void* d_ws, size_t ws_size,
                              hipStream_t stream) {
  const float* X   = (const float*)d_in[0];
  const float* adj = (const float*)d_in[1];
  const float* Ws  = (const float*)d_in[2];
  const float* bs  = (const float*)d_in[3];
  const float* gms = (const float*)d_in[4];
  const float* bts = (const float*)d_in[5];
  float* out = (float*)d_out;

  // ws: adjTt bf16 (134MB) | hwTt ping-pong bf16 (2 x 8.4MB) | WT bf16 (96KB)
  unsigned short* adjTt = (unsigned short*)d_ws;
  unsigned short* hwT0  = adjTt + (size_t)BB * NN * NN;
  unsigned short* hwT1  = hwT0 + (size_t)BB * DD * NN;
  unsigned short* WT    = hwT1 + (size_t)BB * DD * NN;

  k_wt<<<dim3(2, 2, 3), 256, 0, stream>>>(Ws, WT);
  k_pre<<<dim3(288, BB), 256, 0, stream>>>(adj, adjTt, X, WT, hwT0);
  for (int l = 0; l < 3; ++l) {
    const float* res = (l == 0) ? X : (const float*)out;
    const unsigned short* WTn = WT + (size_t)((l < 2) ? (l + 1) : 0) * DD * DD;
    unsigned short* hin  = (l & 1) ? hwT1 : hwT0;
    unsigned short* hout = (l & 1) ? hwT0 : hwT1;
    k_layer<<<dim3(NN / 64, BB), 256, 0, stream>>>(adjTt, hin, res, bs + l * DD,
                                                   gms + l * DD, bts + l * DD,
                                                   WTn, out, hout, (l < 2) ? 1 : 0);
  }
}

// Round 6
// 532.337 us; speedup vs baseline: 1.3271x; 1.0034x over previous
//
#include <hip/hip_runtime.h>

#define BB 16
#define NN 2048
#define DD 128

typedef __attribute__((ext_vector_type(8))) __bf16 bf16x8;
typedef __attribute__((ext_vector_type(4))) float f32x4;
typedef __attribute__((ext_vector_type(4))) unsigned int u32x4;
typedef __attribute__((address_space(3))) unsigned int lds_u32;
typedef __attribute__((address_space(1))) const unsigned int glob_u32;

static __device__ __forceinline__ unsigned short f2b(float f) {
  union { float f; unsigned int u; } c; c.f = f;
  unsigned int u = c.u;
  unsigned int r = (u + 0x7FFFu + ((u >> 16) & 1u)) >> 16;
  return (unsigned short)r;
}
static __device__ __forceinline__ float b2f(unsigned short u) {
  union { unsigned int u; float f; } c; c.u = ((unsigned int)u) << 16;
  return c.f;
}

// ===== Tiled layouts (all K-loop staging streams are contiguous) =====
// adjTt[b][jt][kt][p=0..511]  8KB tiles; chunk p (16B) holds
//   adjT[jt*64 + (p>>3)][kt*64 + ((p&7)^((p>>3)&7))*8 + s]   (XOR swizzle baked in)
// hwTt[b][kt][p=0..1023] 16KB tiles; chunk p holds
//   hwT[e=(p>>3)][kt*64 + ((p&7)^((p>>3)&7))*8 + s]

// WT[l][e][d] = bf16(W[l][d][e])  -- 96 KB total, L2-resident afterwards
__global__ void k_wt(const float* __restrict__ W, unsigned short* __restrict__ WT) {
  __shared__ float t[64][65];
  int l = blockIdx.z, d0 = blockIdx.x * 64, e0 = blockIdx.y * 64;
  int tid = threadIdx.x;
  const float* src = W + (size_t)l * DD * DD;
  for (int p = 0; p < 16; ++p) {
    int idx = p * 256 + tid;
    int d = idx >> 6, e = idx & 63;
    t[e][d] = src[(size_t)(d0 + d) * DD + (e0 + e)];
  }
  __syncthreads();
  unsigned short* dst = WT + (size_t)l * DD * DD;
  for (int p = 0; p < 4; ++p) {
    int idx = p * 256 + tid;
    int e = idx >> 4, d4 = (idx & 15) * 4;
    ushort4 r;
    r.x = f2b(t[e][d4 + 0]); r.y = f2b(t[e][d4 + 1]);
    r.z = f2b(t[e][d4 + 2]); r.w = f2b(t[e][d4 + 3]);
    *(ushort4*)(dst + (size_t)(e0 + e) * DD + (d0 + d4)) = r;
  }
}

// x<256: transpose adj -> tiled adjTt; x>=256: layer-0 gemm1 -> tiled hwTt
__global__ __launch_bounds__(256) void k_pre(const float* __restrict__ adj,
                                             unsigned short* __restrict__ adjTt,
                                             const float* __restrict__ X,
                                             const unsigned short* __restrict__ WT,
                                             unsigned short* __restrict__ hwTt) {
  __shared__ unsigned short t2[64 * 260];  // t2[i][j] bf16, 33.3 KB
  int b = blockIdx.y, x = blockIdx.x, tid = threadIdx.x;
  if (x < 256) {
    int i_t = x >> 3, j_t = x & 7;
    int i0 = i_t * 64, j0 = j_t * 256;
    const float* src = adj + (size_t)b * NN * NN;
#pragma unroll
    for (int p = 0; p < 16; ++p) {
      int idx = p * 256 + tid;
      int i = idx >> 6, jc = (idx & 63) * 4;
      float4 v = *(const float4*)(src + (size_t)(i0 + i) * NN + (j0 + jc));
      unsigned int* d = (unsigned int*)(t2 + i * 260 + jc);
      d[0] = (unsigned int)f2b(v.x) | ((unsigned int)f2b(v.y) << 16);
      d[1] = (unsigned int)f2b(v.z) | ((unsigned int)f2b(v.w) << 16);
    }
    __syncthreads();
#pragma unroll
    for (int pp = 0; pp < 8; ++pp) {
      int idx = pp * 256 + tid;
      int sub = idx >> 9, p = idx & 511;
      int r = p >> 3, g = (p & 7) ^ (r & 7);
      union { u32x4 u; unsigned short h[8]; } ub;
#pragma unroll
      for (int s = 0; s < 8; ++s) ub.h[s] = t2[(g * 8 + s) * 260 + sub * 64 + r];
      size_t tile = ((size_t)(b * 32 + j_t * 4 + sub) * 32 + i_t) * 4096;
      *(u32x4*)(adjTt + tile + p * 8) = ub.u;
    }
  } else {
    int kt = x - 256;
    int i0 = kt * 64;
    int lane = tid & 63, w = tid >> 6;
    int q = lane >> 4, m = lane & 15;
    f32x4 acc[8];
#pragma unroll
    for (int t = 0; t < 8; ++t)
#pragma unroll
      for (int r = 0; r < 4; ++r) acc[t][r] = 0.f;
    int il = w * 16 + m;
    const float* hrow = X + ((size_t)b * NN + i0 + il) * DD;
#pragma unroll
    for (int kk = 0; kk < 4; ++kk) {
      int d0 = kk * 32 + q * 8;
      float4 h0 = *(const float4*)(hrow + d0);
      float4 h1 = *(const float4*)(hrow + d0 + 4);
      union { bf16x8 v; unsigned short s[8]; } ub;
      ub.s[0] = f2b(h0.x); ub.s[1] = f2b(h0.y); ub.s[2] = f2b(h0.z); ub.s[3] = f2b(h0.w);
      ub.s[4] = f2b(h1.x); ub.s[5] = f2b(h1.y); ub.s[6] = f2b(h1.z); ub.s[7] = f2b(h1.w);
#pragma unroll
      for (int mt = 0; mt < 8; ++mt) {
        bf16x8 af = *(const bf16x8*)(WT + (mt * 16 + m) * 128 + d0);
        acc[mt] = __builtin_amdgcn_mfma_f32_16x16x32_bf16(af, ub.v, acc[mt], 0, 0, 0);
      }
    }
    unsigned short* dst = hwTt + ((size_t)b * 32 + kt) * 8192;
#pragma unroll
    for (int mt = 0; mt < 8; ++mt)
#pragma unroll
      for (int r = 0; r < 4; ++r) {
        int e = mt * 16 + q * 4 + r;
        int p = e * 8 + ((il >> 3) ^ (e & 7));
        dst[p * 8 + (il & 7)] = f2b(acc[mt][r]);
      }
  }
}

// Staging macro: stage tile (aSrc/hSrc cursors) into buffer at nb.
#define STAGE(nb)                                                                   \
  {                                                                                 \
    _Pragma("unroll")                                                               \
    for (int it = 0; it < 2; ++it) {                                                \
      __builtin_amdgcn_global_load_lds((glob_u32*)aSrc[it],                         \
                                       (lds_u32*)((nb) + (it * 4 + w) * 512), 16, 0, 0); \
      aSrc[it] += 4096;                                                             \
    }                                                                               \
    _Pragma("unroll")                                                               \
    for (int it = 0; it < 4; ++it) {                                                \
      __builtin_amdgcn_global_load_lds((glob_u32*)hSrc[it],                         \
                                       (lds_u32*)((nb) + 4096 + (it * 4 + w) * 512), 16, 0, 0); \
      hSrc[it] += 8192;                                                             \
    }                                                                               \
  }

// Fused per-layer kernel. K-loop now uses COUNTED vmcnt + raw barriers (T4):
// 3 buffers, depth-2 prefetch. At iter t: stage(t+2), compute(t), then
// s_waitcnt vmcnt(6) (tile t+1's 6 loads done; t+2's 6 still in flight) + s_barrier.
// Loads stay in flight ACROSS barriers -> ~96 KB in flight/CU vs ~40 KB needed.
// The old __syncthreads drained vmcnt(0) every iter = depth-1 pipeline = the 143us.
// Correctness: buffers t,t+1,t+2 distinct mod 3; a buffer's next write is one full
// barrier after its last read; equal load counts per wave (2+4); each wave's
// ds_reads forced complete by its own MFMAs before barrier arrival.
__global__ __launch_bounds__(256) void k_layer(const unsigned short* __restrict__ adjTt,
                                               const unsigned short* __restrict__ hwTt,
                                               const float* __restrict__ res,
                                               const float* __restrict__ bias,
                                               const float* __restrict__ gamma,
                                               const float* __restrict__ beta,
                                               const unsigned short* __restrict__ WTn,
                                               float* __restrict__ outf,
                                               unsigned short* __restrict__ hwTnt,
                                               int doW) {
  __shared__ __align__(16) unsigned short sbuf[3 * 12288];  // 3 x (sA 4096 + sH 8192) = 72KB
  __shared__ float smu[64], srs[64];
  float* z = (float*)sbuf;  // 64x132 f32 = 33.8 KB, alias: staging dead after K-loop

  int tid = threadIdx.x;
  int lane = tid & 63, w = tid >> 6;
  int q = lane >> 4, m = lane & 15;
  int wj = w & 1, we = w >> 1;
  int b = blockIdx.y, jt = blockIdx.x, j0 = jt * 64;
  const unsigned short* At = adjTt + ((size_t)(b * 32 + jt)) * 32 * 4096;
  const unsigned short* Ht = hwTt + (size_t)b * 32 * 8192;

  const unsigned short* aSrc[2];
  const unsigned short* hSrc[4];
#pragma unroll
  for (int it = 0; it < 2; ++it)
    aSrc[it] = At + ((it * 4 + w) * 64 + lane) * 8;
#pragma unroll
  for (int it = 0; it < 4; ++it)
    hSrc[it] = Ht + ((it * 4 + w) * 64 + lane) * 8;

  f32x4 acc[2][4];
#pragma unroll
  for (int i = 0; i < 2; ++i)
#pragma unroll
    for (int j = 0; j < 4; ++j)
#pragma unroll
      for (int r = 0; r < 4; ++r) acc[i][j][r] = 0.f;

  // Prologue: stage tiles 0 and 1; wait only for tile 0 (6 newest = tile 1 stay in flight)
  STAGE(sbuf);
  STAGE(sbuf + 12288);
  asm volatile("s_waitcnt vmcnt(6)" ::: "memory");
  __builtin_amdgcn_s_barrier();

  int bi = 0;
  for (int t = 0; t < 32; ++t) {
    const unsigned short* sA = sbuf + bi * 12288;
    const unsigned short* sH = sA + 4096;
    if (t < 30) {
      int nbi = bi + 2; if (nbi >= 3) nbi -= 3;
      unsigned short* nb = sbuf + nbi * 12288;
      STAGE(nb);
    }
#pragma unroll
    for (int kk = 0; kk < 2; ++kk) {
      bf16x8 af[2], bfr[4];
#pragma unroll
      for (int mt = 0; mt < 2; ++mt) {
        int r = wj * 32 + mt * 16 + m;
        int c = (kk * 4 + q) ^ (r & 7);
        af[mt] = *(const bf16x8*)(sA + r * 64 + c * 8);
      }
#pragma unroll
      for (int nt = 0; nt < 4; ++nt) {
        int r = we * 64 + nt * 16 + m;
        int c = (kk * 4 + q) ^ (r & 7);
        bfr[nt] = *(const bf16x8*)(sH + r * 64 + c * 8);
      }
#pragma unroll
      for (int mt = 0; mt < 2; ++mt)
#pragma unroll
        for (int nt = 0; nt < 4; ++nt)
          acc[mt][nt] = __builtin_amdgcn_mfma_f32_16x16x32_bf16(af[mt], bfr[nt], acc[mt][nt], 0, 0, 0);
    }
    if (t < 30) {
      asm volatile("s_waitcnt vmcnt(6)" ::: "memory");  // tile t+1 resident; t+2 in flight
      __builtin_amdgcn_s_barrier();
    } else if (t == 30) {
      asm volatile("s_waitcnt vmcnt(0)" ::: "memory");  // tile 31 resident
      __builtin_amdgcn_s_barrier();
    }
    bi = bi + 1; if (bi == 3) bi = 0;
  }
  __syncthreads();  // full drain: all waves done reading buffers before z aliases them

  // E1: spill accumulators (full-K fp32 sums) into z
#pragma unroll
  for (int mt = 0; mt < 2; ++mt)
#pragma unroll
    for (int nt = 0; nt < 4; ++nt)
#pragma unroll
      for (int r = 0; r < 4; ++r) {
        int row = wj * 32 + mt * 16 + q * 4 + r;
        int col = we * 64 + nt * 16 + m;
        z[row * 132 + col] = acc[mt][nt][r];
      }
  __syncthreads();

  // E2: z += res + bias
  size_t base = ((size_t)b * NN + j0) * DD;
#pragma unroll
  for (int p = 0; p < 4; ++p) {
    int idx = p * 256 + tid;
    int j = idx >> 4, c8 = (idx & 15) * 8;
    size_t off = (size_t)j * DD + c8;
    const float4* r4 = (const float4*)(res + base + off);
    float4 r0 = r4[0], r1 = r4[1];
    const float4* bi4 = (const float4*)(bias + c8);
    float4 b0 = bi4[0], b1 = bi4[1];
    float* zz = &z[j * 132 + c8];
    zz[0] += r0.x + b0.x; zz[1] += r0.y + b0.y;
    zz[2] += r0.z + b0.z; zz[3] += r0.w + b0.w;
    zz[4] += r1.x + b1.x; zz[5] += r1.y + b1.y;
    zz[6] += r1.z + b1.z; zz[7] += r1.w + b1.w;
  }
  __syncthreads();

  // E3: LN stats (4 threads per row, interleaved reads; 2-way bank = free)
  {
    int j = tid >> 2, s = tid & 3;
    float sum = 0.f, sq = 0.f;
#pragma unroll
    for (int k = 0; k < 32; ++k) {
      float v = z[j * 132 + s + 4 * k];
      sum += v; sq += v * v;
    }
    sum += __shfl_xor(sum, 1); sq += __shfl_xor(sq, 1);
    sum += __shfl_xor(sum, 2); sq += __shfl_xor(sq, 2);
    if (s == 0) {
      float mu = sum * (1.f / 128.f);
      float var = sq * (1.f / 128.f) - mu * mu;
      smu[j] = mu;
      srs[j] = rsqrtf(var + 1e-5f);
    }
  }
  __syncthreads();

  // E4: normalize + ReLU -> outf; keep h in z for gemm1
  {
    int e = tid & 127;
    float g = gamma[e], bt = beta[e];
#pragma unroll
    for (int p = 0; p < 32; ++p) {
      int idx = p * 256 + tid;
      int j = idx >> 7;
      float v = (z[j * 132 + e] - smu[j]) * srs[j] * g + bt;
      v = fmaxf(v, 0.f);
      outf[base + idx] = v;
      z[j * 132 + e] = v;   // same thread, same slot: no race
    }
  }
  if (!doW) return;
  __syncthreads();

  // E5: gemm1 -> tiled hwTnt tile (kt = jt); WTn fragments direct from global
  f32x4 acc2[8];
#pragma unroll
  for (int t = 0; t < 8; ++t)
#pragma unroll
    for (int r = 0; r < 4; ++r) acc2[t][r] = 0.f;
  int il = w * 16 + m;
  const float* hrow = &z[il * 132];
#pragma unroll
  for (int kk = 0; kk < 4; ++kk) {
    int d0 = kk * 32 + q * 8;
    float4 h0 = *(const float4*)(hrow + d0);
    float4 h1 = *(const float4*)(hrow + d0 + 4);
    union { bf16x8 v; unsigned short s[8]; } ub;
    ub.s[0] = f2b(h0.x); ub.s[1] = f2b(h0.y); ub.s[2] = f2b(h0.z); ub.s[3] = f2b(h0.w);
    ub.s[4] = f2b(h1.x); ub.s[5] = f2b(h1.y); ub.s[6] = f2b(h1.z); ub.s[7] = f2b(h1.w);
#pragma unroll
    for (int mt = 0; mt < 8; ++mt) {
      bf16x8 af = *(const bf16x8*)(WTn + (mt * 16 + m) * 128 + d0);
      acc2[mt] = __builtin_amdgcn_mfma_f32_16x16x32_bf16(af, ub.v, acc2[mt], 0, 0, 0);
    }
  }
  unsigned short* dst = hwTnt + ((size_t)b * 32 + jt) * 8192;
#pragma unroll
  for (int mt = 0; mt < 8; ++mt)
#pragma unroll
    for (int r = 0; r < 4; ++r) {
      int e = mt * 16 + q * 4 + r;
      int p = e * 8 + ((il >> 3) ^ (e & 7));
      dst[p * 8 + (il & 7)] = f2b(acc2[mt][r]);
    }
}

extern "C" void kernel_launch(void* const* d_in, const int* in_sizes, int n_in,
                              void* d_out, int out_size, void* d_ws, size_t ws_size,
                              hipStream_t stream) {
  const float* X   = (const float*)d_in[0];
  const float* adj = (const float*)d_in[1];
  const float* Ws  = (const float*)d_in[2];
  const float* bs  = (const float*)d_in[3];
  const float* gms = (const float*)d_in[4];
  const float* bts = (const float*)d_in[5];
  float* out = (float*)d_out;

  // ws: adjTt bf16 (134MB) | hwTt ping-pong bf16 (2 x 8.4MB) | WT bf16 (96KB)
  unsigned short* adjTt = (unsigned short*)d_ws;
  unsigned short* hwT0  = adjTt + (size_t)BB * NN * NN;
  unsigned short* hwT1  = hwT0 + (size_t)BB * DD * NN;
  unsigned short* WT    = hwT1 + (size_t)BB * DD * NN;

  k_wt<<<dim3(2, 2, 3), 256, 0, stream>>>(Ws, WT);
  k_pre<<<dim3(288, BB), 256, 0, stream>>>(adj, adjTt, X, WT, hwT0);
  for (int l = 0; l < 3; ++l) {
    const float* res = (l == 0) ? X : (const float*)out;
    const unsigned short* WTn = WT + (size_t)((l < 2) ? (l + 1) : 0) * DD * DD;
    unsigned short* hin  = (l & 1) ? hwT1 : hwT0;
    unsigned short* hout = (l & 1) ? hwT0 : hwT1;
    k_layer<<<dim3(NN / 64, BB), 256, 0, stream>>>(adjTt, hin, res, bs + l * DD,
                                                   gms + l * DD, bts + l * DD,
                                                   WTn, out, hout, (l < 2) ? 1 : 0);
  }
}